// Round 1
// baseline (120.338 us; speedup 1.0000x reference)
//
#include <hip/hip_runtime.h>

#define N 4096
#define D 256
#define MARGIN 0.3f
#define BIG 10000.0f

typedef _Float16 f16x8 __attribute__((ext_vector_type(8)));
typedef _Float16 f16x4 __attribute__((ext_vector_type(4)));
typedef float floatx16 __attribute__((ext_vector_type(16)));

__device__ inline void atomicMaxFloatPos(float* a, float v) {
    atomicMax((int*)a, __float_as_int(v));   // valid: all values >= 0
}
__device__ inline void atomicMinFloatPos(float* a, float v) {
    atomicMin((int*)a, __float_as_int(v));
}

// async 16B global -> LDS (wave-uniform LDS base + lane*16)
__device__ inline void gl_lds16(const void* g, void* l) {
    __builtin_amdgcn_global_load_lds(
        (const __attribute__((address_space(1))) unsigned int*)g,
        (__attribute__((address_space(3))) unsigned int*)l, 16, 0, 0);
}

// Wave per row: convert x -> fp16 Xf (RNE), sq from the CONVERTED values
// (so the Gram diagonal cancels exactly), init ap/ang/anl.
__global__ __launch_bounds__(256) void prep_kernel(const float* __restrict__ x,
                                                   float* __restrict__ sq,
                                                   _Float16* __restrict__ Xf,
                                                   float* ap, float* ang, float* anl) {
    const int wave = threadIdx.x >> 6, lane = threadIdx.x & 63;
    const int row = blockIdx.x * 4 + wave;
    const float4 v = *(const float4*)(x + (size_t)row * D + lane * 4);
    f16x4 h;
    h[0] = (_Float16)v.x; h[1] = (_Float16)v.y;
    h[2] = (_Float16)v.z; h[3] = (_Float16)v.w;
    *(f16x4*)(Xf + (size_t)row * D + lane * 4) = h;
    const float c0 = (float)h[0], c1 = (float)h[1], c2 = (float)h[2], c3 = (float)h[3];
    float s = c0 * c0 + c1 * c1 + c2 * c2 + c3 * c3;
    #pragma unroll
    for (int off = 32; off; off >>= 1) s += __shfl_down(s, off);
    if (lane == 0) sq[row] = s;
    if (threadIdx.x < 4) {
        const int i = blockIdx.x * 4 + threadIdx.x;
        ap[i] = 0.0f; ang[i] = BIG; anl[i] = BIG;
    }
}

// One wave (64 threads) per 64x64 output tile. Wave-private 16 KB LDS,
// NO barriers.
// v2 K-loop: 8 stages of BK=32, double-buffered in the SAME 16 KB
// (two 8-KB buffers: A 64x32 fp16 + B 64x32 fp16 each). Stage s+2's DMA
// is issued at the end of stage s; the wait is a COUNTED vmcnt(8) (one
// stage of loads stays in flight across the compute) — never a full
// drain except the last stage. LDS rows are 64 B; 16B quad q of row r
// stored at phys quad q ^ (r&3) (conflict-free b128: 64 lanes cover all
// 8 quad-banks evenly).
// Epilogue: phase A computes d, nontemporal coalesced global stores
// (dist is write-only -> don't evict Xf from L2) + swizzled LDS f32
// tile; phase B: lane = row, serial reduce, 3 atomics. No shuffles.
__global__ __launch_bounds__(64) void dist_kernel(const _Float16* __restrict__ Xf,
                                                  const int* __restrict__ tgt,
                                                  const float* __restrict__ sq,
                                                  float* __restrict__ dist,
                                                  float* ap, float* ang, float* anl) {
    __shared__ _Float16 lds[8192];          // 16 KiB total
    float* ldsC = (float*)lds;              // epilogue: 64 x 64 f32 (16 KiB)

    const int lane = threadIdx.x;
    const int row0 = blockIdx.y * 64;
    const int col0 = blockIdx.x * 64;

    // DMA per-lane source constants: per 1-KB instr, 16 rows x 64 B;
    // lane -> (row-in-16 = lane>>2, phys quad p = lane&3); fetch logical
    // quad q = p ^ (r&3) so fragment reads are conflict-free.
    const int drow = lane >> 2;                    // 0..15
    const int q    = (lane & 3) ^ (drow & 3);      // logical quad 0..3

    floatx16 acc[2][2];
    #pragma unroll
    for (int mt = 0; mt < 2; ++mt)
        #pragma unroll
        for (int nt = 0; nt < 2; ++nt)
            #pragma unroll
            for (int r = 0; r < 16; ++r) acc[mt][nt][r] = 0.0f;

    const int m0 = lane & 31;
    const int m1 = 32 + m0;
    const int hi = lane >> 5;
    const int fsw = (m0 & 3);                      // frag-read swizzle key (m1&3 == m0&3)

    // ---- stage DMA issue: 8 x gl_lds16 (4 A + 4 B), buffer = s&1 ----
    #define ISSUE_STAGE(s)                                                            \
    do {                                                                              \
        _Float16* buf_ = lds + ((s) & 1) * 4096;                                      \
        const int k0_ = (s) * 32;                                                     \
        _Pragma("unroll")                                                             \
        for (int d = 0; d < 4; ++d) {                                                 \
            const int r_ = d * 16 + drow;                                             \
            gl_lds16(Xf + (size_t)(row0 + r_) * D + k0_ + q * 8, buf_ + d * 512);     \
            gl_lds16(Xf + (size_t)(col0 + r_) * D + k0_ + q * 8, buf_ + 2048 + d * 512); \
        }                                                                             \
    } while (0)

    ISSUE_STAGE(0);
    ISSUE_STAGE(1);

    #pragma unroll
    for (int s = 0; s < 8; ++s) {
        // wait for stage s's 8 loads; leave the next stage's 8 in flight
        if (s < 7) { __asm__ volatile("s_waitcnt vmcnt(8)" ::: "memory"); }
        else       { __asm__ volatile("s_waitcnt vmcnt(0)" ::: "memory"); }

        const _Float16* buf = lds + (s & 1) * 4096;
        __builtin_amdgcn_s_setprio(1);
        #pragma unroll
        for (int ks = 0; ks < 2; ++ks) {
            const int lq = ks * 2 + hi;            // logical quad 0..3
            const int po = (lq ^ fsw) << 3;        // phys 16B-quad elem offset
            f16x8 a0 = *(const f16x8*)(buf + m0 * 32 + po);
            f16x8 a1 = *(const f16x8*)(buf + m1 * 32 + po);
            f16x8 b0 = *(const f16x8*)(buf + 2048 + m0 * 32 + po);
            f16x8 b1 = *(const f16x8*)(buf + 2048 + m1 * 32 + po);
            acc[0][0] = __builtin_amdgcn_mfma_f32_32x32x16_f16(a0, b0, acc[0][0], 0, 0, 0);
            acc[0][1] = __builtin_amdgcn_mfma_f32_32x32x16_f16(a0, b1, acc[0][1], 0, 0, 0);
            acc[1][0] = __builtin_amdgcn_mfma_f32_32x32x16_f16(a1, b0, acc[1][0], 0, 0, 0);
            acc[1][1] = __builtin_amdgcn_mfma_f32_32x32x16_f16(a1, b1, acc[1][1], 0, 0, 0);
        }
        __builtin_amdgcn_s_setprio(0);

        if (s < 6) {
            // buffer (s&1) fully consumed (MFMAs retired its ds_reads);
            // guard then refill it with stage s+2.
            __asm__ volatile("s_waitcnt lgkmcnt(0)" ::: "memory");
            ISSUE_STAGE(s + 2);
        }
        __asm__ volatile("" ::: "memory");   // pin stage ordering
    }
    #undef ISSUE_STAGE

    // ---- Epilogue phase A: d = sqrt(sqi + sqj - 2*dot); nontemporal global
    // stores (coalesced dwords) + swizzled LDS f32 tile. C/D layout:
    // col = lane&31, row = (r&3) + 8*(r>>2) + 4*(lane>>5).
    const int gc0 = col0 + m0, gc1 = col0 + 32 + m0;
    const float sqc0 = sq[gc0], sqc1 = sq[gc1];
    const int rl_base = 4 * hi;

    #pragma unroll
    for (int mt = 0; mt < 2; ++mt) {
        #pragma unroll
        for (int r = 0; r < 16; ++r) {
            const int row_l = mt * 32 + (r & 3) + 8 * (r >> 2) + rl_base;
            const int grow  = row0 + row_l;
            const float sqi = sq[grow];
            const float d0 = sqrtf(fmaxf(sqi + sqc0 - 2.0f * acc[mt][0][r], 0.0f));
            const float d1 = sqrtf(fmaxf(sqi + sqc1 - 2.0f * acc[mt][1][r], 0.0f));
            __builtin_nontemporal_store(d0, dist + (size_t)grow * N + gc0);
            __builtin_nontemporal_store(d1, dist + (size_t)grow * N + gc1);
            const int sw = row_l & 15;
            ldsC[row_l * 64 + (((m0 >> 2) ^ sw) << 2) + (m0 & 3)] = d0;
            ldsC[row_l * 64 + ((((m0 + 32) >> 2) ^ sw) << 2) + (m0 & 3)] = d1;
        }
    }
    __asm__ volatile("s_waitcnt lgkmcnt(0)" ::: "memory");

    // ---- Phase B: lane = row, serial reduce over 64 cols, 3 atomics.
    const int grow = row0 + lane;
    const int ti   = tgt[grow];
    float mx = 0.0f, mg = BIG, ml = BIG;
    #pragma unroll
    for (int j = 0; j < 16; ++j) {
        const int4  t4 = *(const int4*)&tgt[col0 + j * 4];    // uniform addr
        const float4 d4 = *(const float4*)&ldsC[lane * 64 + ((j ^ (lane & 15)) << 2)];
        if (t4.x == ti) mx = fmaxf(mx, d4.x); else if (t4.x > ti) mg = fminf(mg, d4.x); else ml = fminf(ml, d4.x);
        if (t4.y == ti) mx = fmaxf(mx, d4.y); else if (t4.y > ti) mg = fminf(mg, d4.y); else ml = fminf(ml, d4.y);
        if (t4.z == ti) mx = fmaxf(mx, d4.z); else if (t4.z > ti) mg = fminf(mg, d4.z); else ml = fminf(ml, d4.z);
        if (t4.w == ti) mx = fmaxf(mx, d4.w); else if (t4.w > ti) mg = fminf(mg, d4.w); else ml = fminf(ml, d4.w);
    }
    atomicMaxFloatPos(&ap[grow], mx);
    atomicMinFloatPos(&ang[grow], mg);
    atomicMinFloatPos(&anl[grow], ml);
}

// One block: histogram (packed wave reduce), then loss/cnt, write outputs.
__global__ __launch_bounds__(1024) void finish_kernel(const float* __restrict__ ap,
                                                      const float* __restrict__ ang,
                                                      const float* __restrict__ anl,
                                                      const int* __restrict__ tgt,
                                                      float* __restrict__ out) {
    __shared__ int hist[4];
    __shared__ unsigned hsum[2][16];
    __shared__ float wsum[16];
    __shared__ int wcnt[16];
    const int tid = threadIdx.x, lane = tid & 63, wv = tid >> 6;

    const int4 t4 = *(const int4*)&tgt[tid * 4];
    int c[4] = {0, 0, 0, 0};
    c[t4.x & 3]++; c[t4.y & 3]++; c[t4.z & 3]++; c[t4.w & 3]++;
    unsigned p01 = (unsigned)c[0] | ((unsigned)c[1] << 16);
    unsigned p23 = (unsigned)c[2] | ((unsigned)c[3] << 16);
    #pragma unroll
    for (int off = 32; off; off >>= 1) {
        p01 += __shfl_down(p01, off);
        p23 += __shfl_down(p23, off);
    }
    if (lane == 0) { hsum[0][wv] = p01; hsum[1][wv] = p23; }
    __syncthreads();
    if (tid == 0) {
        unsigned a = 0, b = 0;
        for (int i = 0; i < 16; ++i) { a += hsum[0][i]; b += hsum[1][i]; }
        hist[0] = a & 0xFFFF; hist[1] = a >> 16;
        hist[2] = b & 0xFFFF; hist[3] = b >> 16;
    }
    __syncthreads();

    float term = 0.0f; int cc = 0;
    const int lab[4] = {t4.x & 3, t4.y & 3, t4.z & 3, t4.w & 3};
    #pragma unroll
    for (int j = 0; j < 4; ++j) {
        const int i = tid * 4 + j;
        term += fmaxf(ap[i] - fabsf(ang[i] - anl[i]) + MARGIN, 0.0f);
        cc += (hist[lab[j]] == 1) ? 1 : 0;
    }
    #pragma unroll
    for (int off = 32; off; off >>= 1) {
        term += __shfl_down(term, off);
        cc   += __shfl_down(cc, off);
    }
    if (lane == 0) { wsum[wv] = term; wcnt[wv] = cc; }
    __syncthreads();
    if (tid == 0) {
        float ls = 0.0f; int cs = 0;
        for (int i = 0; i < 16; ++i) { ls += wsum[i]; cs += wcnt[i]; }
        out[0] = ls * (1.0f / N);
        out[1 + (size_t)N * N] = (float)cs;
    }
}

extern "C" void kernel_launch(void* const* d_in, const int* in_sizes, int n_in,
                              void* d_out, int out_size, void* d_ws, size_t ws_size,
                              hipStream_t stream) {
    const float* x   = (const float*)d_in[0];
    const int*   tgt = (const int*)d_in[1];
    float* out = (float*)d_out;
    char*  ws  = (char*)d_ws;

    _Float16* Xf  = (_Float16*)ws;                    // 2 MiB, 16B-aligned
    float*    sq  = (float*)(ws + 2097152);
    float*    ap  = sq + 4096;
    float*    ang = sq + 8192;
    float*    anl = sq + 12288;

    prep_kernel<<<N / 4, 256, 0, stream>>>(x, sq, Xf, ap, ang, anl);
    dim3 grid(N / 64, N / 64);
    dist_kernel<<<grid, 64, 0, stream>>>(Xf, tgt, sq, out + 1, ap, ang, anl);
    finish_kernel<<<1, 1024, 0, stream>>>(ap, ang, anl, tgt, out);
}

// Round 2
// 120.206 us; speedup vs baseline: 1.0011x; 1.0011x over previous
//
#include <hip/hip_runtime.h>

#define N 4096
#define D 256
#define MARGIN 0.3f
#define BIG 10000.0f

typedef _Float16 f16x8 __attribute__((ext_vector_type(8)));
typedef _Float16 f16x4 __attribute__((ext_vector_type(4)));
typedef float floatx16 __attribute__((ext_vector_type(16)));

__device__ inline void atomicMaxFloatPos(float* a, float v) {
    atomicMax((int*)a, __float_as_int(v));   // valid: all values >= 0
}
__device__ inline void atomicMinFloatPos(float* a, float v) {
    atomicMin((int*)a, __float_as_int(v));
}

// async 16B global -> LDS (wave-uniform LDS base + lane*16)
__device__ inline void gl_lds16(const void* g, void* l) {
    __builtin_amdgcn_global_load_lds(
        (const __attribute__((address_space(1))) unsigned int*)g,
        (__attribute__((address_space(3))) unsigned int*)l, 16, 0, 0);
}

// Wave per row: convert x -> fp16 Xf (RNE), sq from the CONVERTED values
// (so the Gram diagonal cancels exactly), init ap/ang/anl.
__global__ __launch_bounds__(256) void prep_kernel(const float* __restrict__ x,
                                                   float* __restrict__ sq,
                                                   _Float16* __restrict__ Xf,
                                                   float* ap, float* ang, float* anl) {
    const int wave = threadIdx.x >> 6, lane = threadIdx.x & 63;
    const int row = blockIdx.x * 4 + wave;
    const float4 v = *(const float4*)(x + (size_t)row * D + lane * 4);
    f16x4 h;
    h[0] = (_Float16)v.x; h[1] = (_Float16)v.y;
    h[2] = (_Float16)v.z; h[3] = (_Float16)v.w;
    *(f16x4*)(Xf + (size_t)row * D + lane * 4) = h;
    const float c0 = (float)h[0], c1 = (float)h[1], c2 = (float)h[2], c3 = (float)h[3];
    float s = c0 * c0 + c1 * c1 + c2 * c2 + c3 * c3;
    #pragma unroll
    for (int off = 32; off; off >>= 1) s += __shfl_down(s, off);
    if (lane == 0) sq[row] = s;
    if (threadIdx.x < 4) {
        const int i = blockIdx.x * 4 + threadIdx.x;
        ap[i] = 0.0f; ang[i] = BIG; anl[i] = BIG;
    }
}

// One wave (64 threads) per 64x64 output tile. Wave-private 8 KB LDS,
// NO barriers, single-buffered BK=32 staging.
// LDS layout: 64 rows x 128 B; row r = [A-row(row0+r) k-slice 64B || B-row
// (col0+r) k-slice 64B], as 8 16B quads; logical quad l of row r stored at
// phys quad l ^ (r&7)  -> conflict-free b128 frag reads (8-lane batches span
// all 32 banks, same as the proven v0 key).
// 8 stages of BK=32: issue 8 x gl_lds16 (1 KB each), drain vmcnt(0), 8 MFMAs.
// Drains are exposed per-wave but covered by TLP: 8 KB LDS -> 16 blocks/CU
// (2x the old 16 KB kernel).
// Epilogue: NO LDS. dist is symmetric, so we reduce DOWN COLUMNS (anchor =
// column), which is native to the MFMA C layout (col = lane&31). Row labels
// come from two __ballot bit-packs; combine hi-halves via __shfl_xor(32);
// 6 atomics from lanes 0..31.
__global__ __launch_bounds__(64) void dist_kernel(const _Float16* __restrict__ Xf,
                                                  const int* __restrict__ tgt,
                                                  const float* __restrict__ sq,
                                                  float* __restrict__ dist,
                                                  float* ap, float* ang, float* anl) {
    __shared__ _Float16 lds[4096];          // 8 KiB: 64 rows x 64 fp16 (128 B)

    const int lane = threadIdx.x;
    const int row0 = blockIdx.y * 64;
    const int col0 = blockIdx.x * 64;

    // DMA mapping: instr d covers rows 8d..8d+7 (1 KB, lds dest = d*512 elems).
    // lane: g = lane>>3 (row in group), p = lane&7 (phys quad), logical
    // lq = p ^ g; lq<4 -> A operand quad lq, else B operand quad lq-4.
    const int g  = lane >> 3;
    const int p  = lane & 7;
    const int lq = p ^ g;
    const _Float16* src0 = Xf + (size_t)((lq < 4 ? row0 : col0) + g) * D + (lq & 3) * 8;

    floatx16 acc[2][2];
    #pragma unroll
    for (int mt = 0; mt < 2; ++mt)
        #pragma unroll
        for (int nt = 0; nt < 2; ++nt)
            #pragma unroll
            for (int r = 0; r < 16; ++r) acc[mt][nt][r] = 0.0f;

    const int m0 = lane & 31;
    const int hi = lane >> 5;
    const int sw = m0 & 7;                   // frag swizzle key ((32+m0)&7 == m0&7)

    #pragma unroll
    for (int s = 0; s < 8; ++s) {
        const int k0 = s * 32;
        // prior stage's ds_reads must have retired before DMA overwrites
        __asm__ volatile("s_waitcnt lgkmcnt(0)" ::: "memory");
        #pragma unroll
        for (int d = 0; d < 8; ++d)
            gl_lds16(src0 + (size_t)d * 8 * D + k0, lds + d * 512);
        __asm__ volatile("s_waitcnt vmcnt(0)" ::: "memory");

        __builtin_amdgcn_s_setprio(1);
        #pragma unroll
        for (int ks = 0; ks < 2; ++ks) {
            const int la = ks * 2 + hi;                       // A logical quad 0..3
            f16x8 a0 = *(const f16x8*)(lds + m0 * 64        + ((la ^ sw) << 3));
            f16x8 a1 = *(const f16x8*)(lds + (32 + m0) * 64 + ((la ^ sw) << 3));
            f16x8 b0 = *(const f16x8*)(lds + m0 * 64        + (((4 + la) ^ sw) << 3));
            f16x8 b1 = *(const f16x8*)(lds + (32 + m0) * 64 + (((4 + la) ^ sw) << 3));
            acc[0][0] = __builtin_amdgcn_mfma_f32_32x32x16_f16(a0, b0, acc[0][0], 0, 0, 0);
            acc[0][1] = __builtin_amdgcn_mfma_f32_32x32x16_f16(a0, b1, acc[0][1], 0, 0, 0);
            acc[1][0] = __builtin_amdgcn_mfma_f32_32x32x16_f16(a1, b0, acc[1][0], 0, 0, 0);
            acc[1][1] = __builtin_amdgcn_mfma_f32_32x32x16_f16(a1, b1, acc[1][1], 0, 0, 0);
        }
        __builtin_amdgcn_s_setprio(0);
        __asm__ volatile("" ::: "memory");   // pin stage ordering
    }

    // ---- Epilogue: d = sqrt(sqi + sqj - 2*dot); nontemporal coalesced global
    // stores; in-register column reduction (anchor = column; by symmetry of
    // dist this yields the same per-anchor sets: row label tr vs col label tc:
    // tr==tc -> hardest-pos max, tr>tc -> min into ang, tr<tc -> min into anl).
    // C layout: col = lane&31 (+32*nt), row = (r&3) + 8*(r>>2) + 4*hi + 32*mt.
    const int tl = tgt[row0 + lane];
    const unsigned long long pb0 = __ballot(tl & 1);   // bit i = tgt[row0+i] bit0
    const unsigned long long pb1 = __ballot(tl & 2);   // bit i = tgt[row0+i] bit1
    const int tc0 = tgt[col0 + m0], tc1 = tgt[col0 + 32 + m0];
    const int gc0 = col0 + m0,      gc1 = col0 + 32 + m0;
    const float sqc0 = sq[gc0], sqc1 = sq[gc1];
    const int rl_base = 4 * hi;

    float mx0 = 0.0f, mg0 = BIG, ml0 = BIG;
    float mx1 = 0.0f, mg1 = BIG, ml1 = BIG;

    #pragma unroll
    for (int mt = 0; mt < 2; ++mt) {
        #pragma unroll
        for (int r = 0; r < 16; ++r) {
            const int row_l = mt * 32 + (r & 3) + 8 * (r >> 2) + rl_base;
            const int grow  = row0 + row_l;
            const float sqi = sq[grow];
            const float d0 = sqrtf(fmaxf(sqi + sqc0 - 2.0f * acc[mt][0][r], 0.0f));
            const float d1 = sqrtf(fmaxf(sqi + sqc1 - 2.0f * acc[mt][1][r], 0.0f));
            __builtin_nontemporal_store(d0, dist + (size_t)grow * N + gc0);
            __builtin_nontemporal_store(d1, dist + (size_t)grow * N + gc1);
            const int tr = (int)((pb0 >> row_l) & 1) | ((int)((pb1 >> row_l) & 1) << 1);
            mx0 = fmaxf(mx0, (tr == tc0) ? d0 : 0.0f);
            mg0 = fminf(mg0, (tr >  tc0) ? d0 : BIG);
            ml0 = fminf(ml0, (tr <  tc0) ? d0 : BIG);
            mx1 = fmaxf(mx1, (tr == tc1) ? d1 : 0.0f);
            mg1 = fminf(mg1, (tr >  tc1) ? d1 : BIG);
            ml1 = fminf(ml1, (tr <  tc1) ? d1 : BIG);
        }
    }
    // combine the two hi-halves (each reduced 32 of the 64 rows)
    mx0 = fmaxf(mx0, __shfl_xor(mx0, 32));
    mg0 = fminf(mg0, __shfl_xor(mg0, 32));
    ml0 = fminf(ml0, __shfl_xor(ml0, 32));
    mx1 = fmaxf(mx1, __shfl_xor(mx1, 32));
    mg1 = fminf(mg1, __shfl_xor(mg1, 32));
    ml1 = fminf(ml1, __shfl_xor(ml1, 32));

    if (hi == 0) {
        atomicMaxFloatPos(&ap[gc0],  mx0);
        atomicMinFloatPos(&ang[gc0], mg0);
        atomicMinFloatPos(&anl[gc0], ml0);
        atomicMaxFloatPos(&ap[gc1],  mx1);
        atomicMinFloatPos(&ang[gc1], mg1);
        atomicMinFloatPos(&anl[gc1], ml1);
    }
}

// One block: histogram (packed wave reduce), then loss/cnt, write outputs.
__global__ __launch_bounds__(1024) void finish_kernel(const float* __restrict__ ap,
                                                      const float* __restrict__ ang,
                                                      const float* __restrict__ anl,
                                                      const int* __restrict__ tgt,
                                                      float* __restrict__ out) {
    __shared__ int hist[4];
    __shared__ unsigned hsum[2][16];
    __shared__ float wsum[16];
    __shared__ int wcnt[16];
    const int tid = threadIdx.x, lane = tid & 63, wv = tid >> 6;

    const int4 t4 = *(const int4*)&tgt[tid * 4];
    int c[4] = {0, 0, 0, 0};
    c[t4.x & 3]++; c[t4.y & 3]++; c[t4.z & 3]++; c[t4.w & 3]++;
    unsigned p01 = (unsigned)c[0] | ((unsigned)c[1] << 16);
    unsigned p23 = (unsigned)c[2] | ((unsigned)c[3] << 16);
    #pragma unroll
    for (int off = 32; off; off >>= 1) {
        p01 += __shfl_down(p01, off);
        p23 += __shfl_down(p23, off);
    }
    if (lane == 0) { hsum[0][wv] = p01; hsum[1][wv] = p23; }
    __syncthreads();
    if (tid == 0) {
        unsigned a = 0, b = 0;
        for (int i = 0; i < 16; ++i) { a += hsum[0][i]; b += hsum[1][i]; }
        hist[0] = a & 0xFFFF; hist[1] = a >> 16;
        hist[2] = b & 0xFFFF; hist[3] = b >> 16;
    }
    __syncthreads();

    float term = 0.0f; int cc = 0;
    const int lab[4] = {t4.x & 3, t4.y & 3, t4.z & 3, t4.w & 3};
    #pragma unroll
    for (int j = 0; j < 4; ++j) {
        const int i = tid * 4 + j;
        term += fmaxf(ap[i] - fabsf(ang[i] - anl[i]) + MARGIN, 0.0f);
        cc += (hist[lab[j]] == 1) ? 1 : 0;
    }
    #pragma unroll
    for (int off = 32; off; off >>= 1) {
        term += __shfl_down(term, off);
        cc   += __shfl_down(cc, off);
    }
    if (lane == 0) { wsum[wv] = term; wcnt[wv] = cc; }
    __syncthreads();
    if (tid == 0) {
        float ls = 0.0f; int cs = 0;
        for (int i = 0; i < 16; ++i) { ls += wsum[i]; cs += wcnt[i]; }
        out[0] = ls * (1.0f / N);
        out[1 + (size_t)N * N] = (float)cs;
    }
}

extern "C" void kernel_launch(void* const* d_in, const int* in_sizes, int n_in,
                              void* d_out, int out_size, void* d_ws, size_t ws_size,
                              hipStream_t stream) {
    const float* x   = (const float*)d_in[0];
    const int*   tgt = (const int*)d_in[1];
    float* out = (float*)d_out;
    char*  ws  = (char*)d_ws;

    _Float16* Xf  = (_Float16*)ws;                    // 2 MiB, 16B-aligned
    float*    sq  = (float*)(ws + 2097152);
    float*    ap  = sq + 4096;
    float*    ang = sq + 8192;
    float*    anl = sq + 12288;

    prep_kernel<<<N / 4, 256, 0, stream>>>(x, sq, Xf, ap, ang, anl);
    dim3 grid(N / 64, N / 64);
    dist_kernel<<<grid, 64, 0, stream>>>(Xf, tgt, sq, out + 1, ap, ang, anl);
    finish_kernel<<<1, 1024, 0, stream>>>(ap, ang, anl, tgt, out);
}

// Round 3
// 113.213 us; speedup vs baseline: 1.0629x; 1.0618x over previous
//
#include <hip/hip_runtime.h>

#define N 4096
#define D 256
#define MARGIN 0.3f
#define BIG 10000.0f

typedef _Float16 f16x8 __attribute__((ext_vector_type(8)));
typedef _Float16 f16x4 __attribute__((ext_vector_type(4)));
typedef float floatx16 __attribute__((ext_vector_type(16)));

__device__ inline void atomicMaxFloatPos(float* a, float v) {
    atomicMax((int*)a, __float_as_int(v));   // valid: all values >= 0
}
__device__ inline void atomicMinFloatPos(float* a, float v) {
    atomicMin((int*)a, __float_as_int(v));
}

// async 16B global -> LDS (wave-uniform LDS base + lane*16)
__device__ inline void gl_lds16(const void* g, void* l) {
    __builtin_amdgcn_global_load_lds(
        (const __attribute__((address_space(1))) unsigned int*)g,
        (__attribute__((address_space(3))) unsigned int*)l, 16, 0, 0);
}

// Wave per row: convert x -> fp16 Xf (RNE), sq from the CONVERTED values
// (so the Gram diagonal cancels exactly), init ap/ang/anl.
__global__ __launch_bounds__(256) void prep_kernel(const float* __restrict__ x,
                                                   float* __restrict__ sq,
                                                   _Float16* __restrict__ Xf,
                                                   float* ap, float* ang, float* anl) {
    const int wave = threadIdx.x >> 6, lane = threadIdx.x & 63;
    const int row = blockIdx.x * 4 + wave;
    const float4 v = *(const float4*)(x + (size_t)row * D + lane * 4);
    f16x4 h;
    h[0] = (_Float16)v.x; h[1] = (_Float16)v.y;
    h[2] = (_Float16)v.z; h[3] = (_Float16)v.w;
    *(f16x4*)(Xf + (size_t)row * D + lane * 4) = h;
    const float c0 = (float)h[0], c1 = (float)h[1], c2 = (float)h[2], c3 = (float)h[3];
    float s = c0 * c0 + c1 * c1 + c2 * c2 + c3 * c3;
    #pragma unroll
    for (int off = 32; off; off >>= 1) s += __shfl_down(s, off);
    if (lane == 0) sq[row] = s;
    if (threadIdx.x < 4) {
        const int i = blockIdx.x * 4 + threadIdx.x;
        ap[i] = 0.0f; ang[i] = BIG; anl[i] = BIG;
    }
}

// 4 waves (256 threads) per 128x128 output tile: halves total global->LDS
// staging traffic vs 64x64/1-wave (each staged byte feeds 4 waves).
// LDS 32 KB single-buffered: A panel 128 rows x 64 fp16 (128 B rows) at 0,
// B panel at +16 KB. 16B quad l of row r stored at phys quad l ^ (r&7)
// (proven conflict-free b128 scheme). 4 stages of BK=64: each wave issues
// 8 x gl_lds16 (1 KB each: 8 rows x 128 B), vmcnt(0)+barrier, 16 MFMAs.
// Wave w: (wr,wc) = (w>>1, w&1) -> 64x64 sub-tile; DMA: waves 0/1 stage
// A rows 0-63/64-127, waves 2/3 stage B rows 0-63/64-127.
// Epilogue: NO LDS. anchor = column (valid by symmetry of dist); row labels
// from two __ballot packs; sqi via pre-loaded register + __shfl; hi-halves
// combined with __shfl_xor(32); 6 atomics from lanes 0..31.
__global__ __launch_bounds__(256, 4) void dist_kernel(const _Float16* __restrict__ Xf,
                                                      const int* __restrict__ tgt,
                                                      const float* __restrict__ sq,
                                                      float* __restrict__ dist,
                                                      float* ap, float* ang, float* anl) {
    __shared__ _Float16 lds[16384];         // 32 KiB: A[0..8191], B[8192..16383]

    const int tid  = threadIdx.x;
    const int wv   = tid >> 6;
    const int lane = tid & 63;
    const int row0 = blockIdx.y * 128;
    const int col0 = blockIdx.x * 128;
    const int wr = wv >> 1, wc = wv & 1;

    // DMA mapping: instr d of wave wv covers panel rows ((wv&1)*64 + d*8 ..+7).
    // lane: g = lane>>3 (row in 8-group), p = lane&7 (phys quad), fetch
    // logical quad lq = p ^ g (row&7 == g since row-base is a multiple of 8).
    const int g = lane >> 3, p = lane & 7, lq = p ^ g;
    const int selrow = (wv < 2 ? row0 : col0) + (wv & 1) * 64 + g;
    const _Float16* src0 = Xf + (size_t)selrow * D + lq * 8;
    _Float16* dst0 = lds + wv * 8 * 512;    // instr d -> +d*512 elems (1 KB)

    // Epilogue scalars prefetched (latency hides under K-loop).
    const int m0 = lane & 31;
    const int hi = lane >> 5;
    const int sw = m0 & 7;
    const int rowbase = row0 + wr * 64;
    const int colbase = col0 + wc * 64;
    const int tl = tgt[rowbase + lane];
    const float sq_r = sq[rowbase + lane];
    const unsigned long long pb0 = __ballot(tl & 1);
    const unsigned long long pb1 = __ballot(tl & 2);
    const int gc0 = colbase + m0, gc1 = colbase + 32 + m0;
    const int tc0 = tgt[gc0], tc1 = tgt[gc1];
    const float sqc0 = sq[gc0], sqc1 = sq[gc1];

    floatx16 acc[2][2];
    #pragma unroll
    for (int mt = 0; mt < 2; ++mt)
        #pragma unroll
        for (int nt = 0; nt < 2; ++nt)
            #pragma unroll
            for (int r = 0; r < 16; ++r) acc[mt][nt][r] = 0.0f;

    const _Float16* ldsA0 = lds + (wr * 64 + m0) * 64;
    const _Float16* ldsA1 = lds + (wr * 64 + 32 + m0) * 64;
    const _Float16* ldsB0 = lds + 8192 + (wc * 64 + m0) * 64;
    const _Float16* ldsB1 = lds + 8192 + (wc * 64 + 32 + m0) * 64;

    #pragma unroll
    for (int s = 0; s < 4; ++s) {
        if (s) {    // all waves' frag reads of stage s-1 must retire first
            __asm__ volatile("s_waitcnt lgkmcnt(0)" ::: "memory");
            __builtin_amdgcn_s_barrier();
        }
        const int k0 = s * 64;
        #pragma unroll
        for (int d = 0; d < 8; ++d)
            gl_lds16(src0 + (size_t)d * 8 * D + k0, dst0 + d * 512);
        __asm__ volatile("s_waitcnt vmcnt(0)" ::: "memory");
        __builtin_amdgcn_s_barrier();

        __builtin_amdgcn_s_setprio(1);
        #pragma unroll
        for (int ks = 0; ks < 4; ++ks) {
            const int la = ks * 2 + hi;                 // logical quad 0..7
            const int po = (la ^ sw) << 3;
            f16x8 a0 = *(const f16x8*)(ldsA0 + po);
            f16x8 a1 = *(const f16x8*)(ldsA1 + po);
            f16x8 b0 = *(const f16x8*)(ldsB0 + po);
            f16x8 b1 = *(const f16x8*)(ldsB1 + po);
            acc[0][0] = __builtin_amdgcn_mfma_f32_32x32x16_f16(a0, b0, acc[0][0], 0, 0, 0);
            acc[0][1] = __builtin_amdgcn_mfma_f32_32x32x16_f16(a0, b1, acc[0][1], 0, 0, 0);
            acc[1][0] = __builtin_amdgcn_mfma_f32_32x32x16_f16(a1, b0, acc[1][0], 0, 0, 0);
            acc[1][1] = __builtin_amdgcn_mfma_f32_32x32x16_f16(a1, b1, acc[1][1], 0, 0, 0);
        }
        __builtin_amdgcn_s_setprio(0);
        __asm__ volatile("" ::: "memory");   // pin stage ordering
    }

    // ---- Epilogue: d = sqrt(sqi + sqj - 2*dot); nontemporal coalesced global
    // stores; in-register column reduction (anchor = column).
    // C layout: col = lane&31 (+32*nt), row = (r&3) + 8*(r>>2) + 4*hi + 32*mt.
    const int rl_base = 4 * hi;

    float mx0 = 0.0f, mg0 = BIG, ml0 = BIG;
    float mx1 = 0.0f, mg1 = BIG, ml1 = BIG;

    #pragma unroll
    for (int mt = 0; mt < 2; ++mt) {
        #pragma unroll
        for (int r = 0; r < 16; ++r) {
            const int row_l = mt * 32 + (r & 3) + 8 * (r >> 2) + rl_base;
            const int grow  = rowbase + row_l;
            const float sqi = __shfl(sq_r, row_l);
            const float d0 = sqrtf(fmaxf(sqi + sqc0 - 2.0f * acc[mt][0][r], 0.0f));
            const float d1 = sqrtf(fmaxf(sqi + sqc1 - 2.0f * acc[mt][1][r], 0.0f));
            __builtin_nontemporal_store(d0, dist + (size_t)grow * N + gc0);
            __builtin_nontemporal_store(d1, dist + (size_t)grow * N + gc1);
            const int tr = (int)((pb0 >> row_l) & 1) | ((int)((pb1 >> row_l) & 1) << 1);
            mx0 = fmaxf(mx0, (tr == tc0) ? d0 : 0.0f);
            mg0 = fminf(mg0, (tr >  tc0) ? d0 : BIG);
            ml0 = fminf(ml0, (tr <  tc0) ? d0 : BIG);
            mx1 = fmaxf(mx1, (tr == tc1) ? d1 : 0.0f);
            mg1 = fminf(mg1, (tr >  tc1) ? d1 : BIG);
            ml1 = fminf(ml1, (tr <  tc1) ? d1 : BIG);
        }
    }
    // combine the two hi-halves (each reduced 32 of the 64 rows)
    mx0 = fmaxf(mx0, __shfl_xor(mx0, 32));
    mg0 = fminf(mg0, __shfl_xor(mg0, 32));
    ml0 = fminf(ml0, __shfl_xor(ml0, 32));
    mx1 = fmaxf(mx1, __shfl_xor(mx1, 32));
    mg1 = fminf(mg1, __shfl_xor(mg1, 32));
    ml1 = fminf(ml1, __shfl_xor(ml1, 32));

    if (hi == 0) {
        atomicMaxFloatPos(&ap[gc0],  mx0);
        atomicMinFloatPos(&ang[gc0], mg0);
        atomicMinFloatPos(&anl[gc0], ml0);
        atomicMaxFloatPos(&ap[gc1],  mx1);
        atomicMinFloatPos(&ang[gc1], mg1);
        atomicMinFloatPos(&anl[gc1], ml1);
    }
}

// One block: histogram (packed wave reduce), then loss/cnt, write outputs.
__global__ __launch_bounds__(1024) void finish_kernel(const float* __restrict__ ap,
                                                      const float* __restrict__ ang,
                                                      const float* __restrict__ anl,
                                                      const int* __restrict__ tgt,
                                                      float* __restrict__ out) {
    __shared__ int hist[4];
    __shared__ unsigned hsum[2][16];
    __shared__ float wsum[16];
    __shared__ int wcnt[16];
    const int tid = threadIdx.x, lane = tid & 63, wv = tid >> 6;

    const int4 t4 = *(const int4*)&tgt[tid * 4];
    int c[4] = {0, 0, 0, 0};
    c[t4.x & 3]++; c[t4.y & 3]++; c[t4.z & 3]++; c[t4.w & 3]++;
    unsigned p01 = (unsigned)c[0] | ((unsigned)c[1] << 16);
    unsigned p23 = (unsigned)c[2] | ((unsigned)c[3] << 16);
    #pragma unroll
    for (int off = 32; off; off >>= 1) {
        p01 += __shfl_down(p01, off);
        p23 += __shfl_down(p23, off);
    }
    if (lane == 0) { hsum[0][wv] = p01; hsum[1][wv] = p23; }
    __syncthreads();
    if (tid == 0) {
        unsigned a = 0, b = 0;
        for (int i = 0; i < 16; ++i) { a += hsum[0][i]; b += hsum[1][i]; }
        hist[0] = a & 0xFFFF; hist[1] = a >> 16;
        hist[2] = b & 0xFFFF; hist[3] = b >> 16;
    }
    __syncthreads();

    float term = 0.0f; int cc = 0;
    const int lab[4] = {t4.x & 3, t4.y & 3, t4.z & 3, t4.w & 3};
    #pragma unroll
    for (int j = 0; j < 4; ++j) {
        const int i = tid * 4 + j;
        term += fmaxf(ap[i] - fabsf(ang[i] - anl[i]) + MARGIN, 0.0f);
        cc += (hist[lab[j]] == 1) ? 1 : 0;
    }
    #pragma unroll
    for (int off = 32; off; off >>= 1) {
        term += __shfl_down(term, off);
        cc   += __shfl_down(cc, off);
    }
    if (lane == 0) { wsum[wv] = term; wcnt[wv] = cc; }
    __syncthreads();
    if (tid == 0) {
        float ls = 0.0f; int cs = 0;
        for (int i = 0; i < 16; ++i) { ls += wsum[i]; cs += wcnt[i]; }
        out[0] = ls * (1.0f / N);
        out[1 + (size_t)N * N] = (float)cs;
    }
}

extern "C" void kernel_launch(void* const* d_in, const int* in_sizes, int n_in,
                              void* d_out, int out_size, void* d_ws, size_t ws_size,
                              hipStream_t stream) {
    const float* x   = (const float*)d_in[0];
    const int*   tgt = (const int*)d_in[1];
    float* out = (float*)d_out;
    char*  ws  = (char*)d_ws;

    _Float16* Xf  = (_Float16*)ws;                    // 2 MiB, 16B-aligned
    float*    sq  = (float*)(ws + 2097152);
    float*    ap  = sq + 4096;
    float*    ang = sq + 8192;
    float*    anl = sq + 12288;

    prep_kernel<<<N / 4, 256, 0, stream>>>(x, sq, Xf, ap, ang, anl);
    dim3 grid(N / 128, N / 128);
    dist_kernel<<<grid, 256, 0, stream>>>(Xf, tgt, sq, out + 1, ap, ang, anl);
    finish_kernel<<<1, 1024, 0, stream>>>(ap, ang, anl, tgt, out);
}